// Round 1
// baseline (1671.553 us; speedup 1.0000x reference)
//
#include <hip/hip_runtime.h>
#include <cfloat>
#include <math.h>

#define BT 64
#define CHN 256
#define HH 56
#define WW 56
#define HW 3136          // 56*56
#define NPIX (BT * HW)   // 200704

// ---------------------------------------------------------------------------
// Kernel A: per-pixel inverse channel-L2 norm (fp64 result).
// v2: thread owns 4 consecutive pixels (float4 loads -> 1KB/wave/instr),
// 4 INDEPENDENT fp64 accumulator chains per thread (was 1 dependent chain),
// 784 blocks (3x CU count). Summation order identical to v1 -> bit-identical.
// ---------------------------------------------------------------------------
__global__ __launch_bounds__(256) void norm_kernel(const float* __restrict__ x,
                                                   double* __restrict__ invn) {
    __shared__ double part[4][256];
    const int t   = threadIdx.x;
    const int q   = t >> 6;          // channel quarter 0..3
    const int grp = t & 63;          // 4-pixel group within block
    const int g0  = blockIdx.x * 256;
    const int gpx = g0 + 4 * grp;    // first global pixel of this thread
    const int b   = gpx / HW;        // 4-px groups never straddle b (HW%4==0)
    const int yx  = gpx - b * HW;
    const float* xb = x + (size_t)b * (CHN * HW) + (size_t)(q * 64) * HW + yx;
    double s0 = 0.0, s1 = 0.0, s2 = 0.0, s3 = 0.0;
    #pragma unroll 8
    for (int c = 0; c < 64; ++c) {
        float4 v = *(const float4*)(xb + (size_t)c * HW);
        s0 += (double)v.x * (double)v.x;
        s1 += (double)v.y * (double)v.y;
        s2 += (double)v.z * (double)v.z;
        s3 += (double)v.w * (double)v.w;
    }
    part[q][4 * grp + 0] = s0;
    part[q][4 * grp + 1] = s1;
    part[q][4 * grp + 2] = s2;
    part[q][4 * grp + 3] = s3;
    __syncthreads();
    double tt = part[0][t] + part[1][t] + part[2][t] + part[3][t];
    invn[g0 + t] = 1.0 / fmax(sqrt(tt), 1e-12);
}

// ---------------------------------------------------------------------------
// Kernel B: correlation volume (81 offsets) + argmax + collapsed softmax.
// Block = 576 threads = 9 waves; wave w owns dy row w (9 dx offsets).
// v2 changes vs v1 (math identical):
//  - DOUBLE-BUFFERED xs/ps (LDS 28.2 -> 46.8 KB; still 3 blocks/CU since
//    occupancy was wave-capped at 27/32 anyway) -> ONE barrier per cc
//    instead of two.
//  - T14 async-stage split: global float4s for cc+1 are issued into
//    registers BEFORE the barrier, so ~200-900cyc load latency hides under
//    the 144 FMAs of iteration cc instead of sitting on the critical path.
//  - red[] transposed (slot = ty + col*16): atomicMax merge bank conflict
//    drops 16-way -> 4-way.
// ---------------------------------------------------------------------------
__global__ __launch_bounds__(576, 6) void corr_kernel(const float* __restrict__ x,
                                                      const double* __restrict__ invn,
                                                      float* __restrict__ out) {
    const int tile = blockIdx.x;   // 0..15
    const int b    = blockIdx.y;   // 0..63
    const int offs0 = (tile & 3);
    const int offs1 = (tile >> 2);
    // tile origins {0,16,32,40}: full coverage of 56 with overlap (idempotent writes)
    const int x0 = (offs0 < 3) ? offs0 * 16 : 40;
    const int y0 = (offs1 < 3) ? offs1 * 16 : 40;
    const int tid = threadIdx.x;

    float* outb = out + (size_t)b * 3 * HW;

    if ((b & 7) == 0) {
        // first frame of each segment: x_post == 0 -> r == 0 -> mot = 0, conf = 0
        if (tid < 256) {
            int py = tid >> 4, px = tid & 15;
            int g = (y0 + py) * WW + (x0 + px);
            outb[g] = 0.f; outb[HW + g] = 0.f; outb[2 * HW + g] = 0.f;
        }
        return;
    }

    const int wave = tid >> 6;     // 0..8 == dy row
    const int lane = tid & 63;
    const int ty  = lane >> 2;     // 0..15 tile row
    const int tx4 = lane & 3;      // pixel group: x-local 4*tx4 .. 4*tx4+3

    __shared__ float  xs[2][4 * 16 * 20];       // [buf][ch][ty][20pad] current tile
    __shared__ float  ps[2][4 * 24 * 36];       // [buf][ch][row][36pad] prev halo
    __shared__ double ivq[24 * 25];             // prev inv-norms (halo), 0 if OOB
    __shared__ double ivp[256];                 // current inv-norms
    __shared__ unsigned long long red[256];     // packed argmax, slot = ty + col*16

    const float*  xcur    = x    + (size_t)b * (CHN * HW);
    const float*  xprv    = x    + (size_t)(b - 1) * (CHN * HW);
    const double* inv_cur = invn + (size_t)b * HW;
    const double* inv_prv = invn + (size_t)(b - 1) * HW;

    // stage inverse norms + init reduction slots (576 = 24*24 exactly)
    {
        int row = tid / 24, col = tid - row * 24;
        int gy = y0 - 4 + row, gx = x0 - 4 + col;
        double v = 0.0;
        if (gy >= 0 && gy < HH && gx >= 0 && gx < WW) v = inv_prv[gy * WW + gx];
        ivq[row * 25 + col] = v;
    }
    if (tid < 256) {
        ivp[tid] = inv_cur[(y0 + (tid >> 4)) * WW + x0 + (tid & 15)];
        red[tid] = 0ULL;
    }

    // staging descriptors (one float4 per thread for ps: 4ch*24rows*6groups = 576)
    int ch_s  = tid / 144;
    int rem_s = tid - ch_s * 144;
    int row_s = rem_s / 6;
    int c4    = rem_s - row_s * 6;
    int gy_s  = y0 - 4 + row_s;
    int gx_s  = x0 - 4 + 4 * c4;
    const bool pv = (gy_s >= 0 && gy_s < HH && gx_s >= 0 && gx_s < WW); // never straddles
    const int    ps_l = (ch_s * 24 + row_s) * 36 + 4 * c4;
    const size_t ps_g = (size_t)ch_s * HW + (pv ? (gy_s * WW + gx_s) : 0);
    int xs_l = 0; size_t xs_g = 0;
    if (tid < 256) {               // 4ch * 16rows * 4groups = 256
        int chx = tid >> 6, r2 = tid & 63, sy = r2 >> 2, sx = r2 & 3;
        xs_l = (chx * 16 + sy) * 20 + 4 * sx;
        xs_g = (size_t)chx * HW + (size_t)(y0 + sy) * WW + x0 + 4 * sx;
    }

    float acc[9][4];
    #pragma unroll
    for (int j = 0; j < 9; ++j)
        #pragma unroll
        for (int t = 0; t < 4; ++t) acc[j][t] = 0.f;

    // prologue: issue cc=0 loads into registers
    float4 pv_reg = make_float4(0.f, 0.f, 0.f, 0.f);
    float4 xv_reg = make_float4(0.f, 0.f, 0.f, 0.f);
    if (pv) pv_reg = *(const float4*)(xprv + ps_g);
    if (tid < 256) xv_reg = *(const float4*)(xcur + xs_g);

    int cur = 0;
    #pragma unroll 2
    for (int cc = 0; cc < 64; ++cc) {
        // stage cc from registers into buf[cur] (other buffer is being read
        // only up to the PREVIOUS barrier -> no hazard, see barrier proof)
        *(float4*)&ps[cur][ps_l] = pv_reg;
        if (tid < 256) *(float4*)&xs[cur][xs_l] = xv_reg;

        // prefetch cc+1: latency hides under this iteration's FMAs
        if (cc < 63) {
            const size_t cb = (size_t)((cc + 1) * 4) * HW;
            if (pv) pv_reg = *(const float4*)(xprv + cb + ps_g);
            if (tid < 256) xv_reg = *(const float4*)(xcur + cb + xs_g);
        }

        __syncthreads();   // single barrier per cc: buf[cur] now visible

        const float* xb = &xs[cur][ty * 20 + 4 * tx4];
        const float* pb = &ps[cur][(ty + wave) * 36 + 4 * tx4];
        #pragma unroll
        for (int ch = 0; ch < 4; ++ch) {
            float4 xq = *(const float4*)(xb + ch * 320);
            float4 w0 = *(const float4*)(pb + ch * 864);
            float4 w1 = *(const float4*)(pb + ch * 864 + 4);
            float4 w2 = *(const float4*)(pb + ch * 864 + 8);
            float win[12] = { w0.x, w0.y, w0.z, w0.w,
                              w1.x, w1.y, w1.z, w1.w,
                              w2.x, w2.y, w2.z, w2.w };
            #pragma unroll
            for (int dx = 0; dx < 9; ++dx) {
                acc[dx][0] = fmaf(xq.x, win[dx + 0], acc[dx][0]);
                acc[dx][1] = fmaf(xq.y, win[dx + 1], acc[dx][1]);
                acc[dx][2] = fmaf(xq.z, win[dx + 2], acc[dx][2]);
                acc[dx][3] = fmaf(xq.w, win[dx + 3], acc[dx][3]);
            }
        }
        cur ^= 1;
    }

    // epilogue: local argmax over this wave's 9 offsets, packed-u64 merge
    const int px0 = ty * 16 + 4 * tx4;
    double ip[4];
    #pragma unroll
    for (int t = 0; t < 4; ++t) ip[t] = ivp[px0 + t];
    unsigned long long best[4] = { 0ULL, 0ULL, 0ULL, 0ULL };
    #pragma unroll
    for (int dx = 0; dx < 9; ++dx) {
        #pragma unroll
        for (int t = 0; t < 4; ++t) {
            double qv = ivq[(ty + wave) * 25 + 4 * tx4 + t + dx];
            float rv = (float)((double)acc[dx][t] * ip[t] * qv);
            unsigned int bits = __float_as_uint(rv);
            unsigned int key = (bits & 0x80000000u) ? ~bits : (bits | 0x80000000u);
            unsigned long long pk =
                ((unsigned long long)key << 32) | (unsigned int)(80 - (wave * 9 + dx));
            if (pk > best[t]) best[t] = pk;   // ascending dx + strict > == first-max
        }
    }
    #pragma unroll
    for (int t = 0; t < 4; ++t)
        atomicMax(&red[ty + ((4 * tx4 + t) << 4)], best[t]);   // bank-spread layout
    __syncthreads();

    if (tid < 256) {
        unsigned long long pk = red[(tid >> 4) + ((tid & 15) << 4)];
        int o = 80 - (int)(pk & 0xffffffffu);
        unsigned int key  = (unsigned int)(pk >> 32);
        unsigned int bits = (key & 0x80000000u) ? (key ^ 0x80000000u) : ~key;
        float v = __uint_as_float(bits);
        float h_idx = (float)(o / 9) - 4.f;
        float v_idx = (float)(o - (o / 9) * 9) - 4.f;
        // gaussian(sigma=0.1) zeroes all non-argmax cells below fp32 resolution:
        // h_cord = h_idx * R/(R+1e-12), R = BETA * r_max
        float R  = 10.f * v;
        float pc = R / (R + 1e-12f);
        int py = tid >> 4, pxl = tid & 15;
        int g = (y0 + py) * WW + (x0 + pxl);
        outb[g]          = h_idx * pc;
        outb[HW + g]     = v_idx * pc;
        outb[2 * HW + g] = v;
    }
}

extern "C" void kernel_launch(void* const* d_in, const int* in_sizes, int n_in,
                              void* d_out, int out_size, void* d_ws, size_t ws_size,
                              hipStream_t stream) {
    const float* x = (const float*)d_in[0];
    float* out = (float*)d_out;
    double* invn = (double*)d_ws;   // 200704 doubles = 1.6 MB

    hipLaunchKernelGGL(norm_kernel, dim3(NPIX / 256), dim3(256), 0, stream,
                       x, invn);
    hipLaunchKernelGGL(corr_kernel, dim3(16, 64), dim3(576), 0, stream,
                       x, invn, out);
}

// Round 2
// 573.732 us; speedup vs baseline: 2.9135x; 2.9135x over previous
//
#include <hip/hip_runtime.h>
#include <cfloat>
#include <math.h>

#define BT 64
#define CHN 256
#define HH 56
#define WW 56
#define HW 3136          // 56*56
#define NPIX (BT * HW)   // 200704

// ---------------------------------------------------------------------------
// Kernel A: per-pixel inverse channel-L2 norm (fp64 result).
// Thread owns 4 consecutive pixels (float4 loads), 4 independent fp64
// accumulator chains. Summation order identical to v1 -> bit-identical.
// ---------------------------------------------------------------------------
__global__ __launch_bounds__(256) void norm_kernel(const float* __restrict__ x,
                                                   double* __restrict__ invn) {
    __shared__ double part[4][256];
    const int t   = threadIdx.x;
    const int q   = t >> 6;          // channel quarter 0..3
    const int grp = t & 63;          // 4-pixel group within block
    const int g0  = blockIdx.x * 256;
    const int gpx = g0 + 4 * grp;    // first global pixel of this thread
    const int b   = gpx / HW;        // 4-px groups never straddle b (HW%4==0)
    const int yx  = gpx - b * HW;
    const float* xb = x + (size_t)b * (CHN * HW) + (size_t)(q * 64) * HW + yx;
    double s0 = 0.0, s1 = 0.0, s2 = 0.0, s3 = 0.0;
    #pragma unroll 8
    for (int c = 0; c < 64; ++c) {
        float4 v = *(const float4*)(xb + (size_t)c * HW);
        s0 += (double)v.x * (double)v.x;
        s1 += (double)v.y * (double)v.y;
        s2 += (double)v.z * (double)v.z;
        s3 += (double)v.w * (double)v.w;
    }
    part[q][4 * grp + 0] = s0;
    part[q][4 * grp + 1] = s1;
    part[q][4 * grp + 2] = s2;
    part[q][4 * grp + 3] = s3;
    __syncthreads();
    double tt = part[0][t] + part[1][t] + part[2][t] + part[3][t];
    invn[g0 + t] = 1.0 / fmax(sqrt(tt), 1e-12);
}

// ---------------------------------------------------------------------------
// direct global->LDS DMA, 16B per lane; LDS dest = wave-uniform base + lane*16
// ---------------------------------------------------------------------------
__device__ __forceinline__ void dma16(const float* g, float* l) {
    __builtin_amdgcn_global_load_lds(
        (const __attribute__((address_space(1))) void*)g,
        (__attribute__((address_space(3))) void*)l, 16, 0, 0);
}

// ---------------------------------------------------------------------------
// Kernel B: correlation volume (81 offsets) + argmax + collapsed softmax.
// Block = 576 threads = 9 waves; wave w owns dy row w (9 dx offsets).
// v3 vs v1 (math identical, FMA order identical):
//  - Staging via __builtin_amdgcn_global_load_lds width=16: NO staging VGPRs
//    (v2's register prefetch spilled: 2.9 GB scratch writes), DMA latency
//    hidden under the compute phase.
//  - UNPADDED LDS layouts xs[4][16][16], ps[4][24][24]: exactly lane-linear
//    (float idx = tid*4) as global_load_lds requires. Read-side bank packing
//    verified same 8-phase full-occupancy pattern as the padded v1 layout.
//  - Double-buffered (xs 8KB + ps 18KB) -> ONE barrier per cc:
//    STAGE(next) -> compute(cur) -> barrier (compiler's vmcnt(0) drain at the
//    barrier lands after a full compute phase of flight time).
//  - OOB halo cells are cc-invariant: pre-zeroed once in both buffers; DMA
//    only writes in-bounds lanes, so zeros persist.
// ---------------------------------------------------------------------------
__global__ __launch_bounds__(576, 6) void corr_kernel(const float* __restrict__ x,
                                                      const double* __restrict__ invn,
                                                      float* __restrict__ out) {
    const int tile = blockIdx.x;   // 0..15
    const int b    = blockIdx.y;   // 0..63
    const int offs0 = (tile & 3);
    const int offs1 = (tile >> 2);
    // tile origins {0,16,32,40}: full coverage of 56 with overlap (idempotent writes)
    const int x0 = (offs0 < 3) ? offs0 * 16 : 40;
    const int y0 = (offs1 < 3) ? offs1 * 16 : 40;
    const int tid = threadIdx.x;

    float* outb = out + (size_t)b * 3 * HW;

    if ((b & 7) == 0) {
        // first frame of each segment: x_post == 0 -> r == 0 -> mot = 0, conf = 0
        if (tid < 256) {
            int py = tid >> 4, px = tid & 15;
            int g = (y0 + py) * WW + (x0 + px);
            outb[g] = 0.f; outb[HW + g] = 0.f; outb[2 * HW + g] = 0.f;
        }
        return;
    }

    const int wave = tid >> 6;     // 0..8 == dy row
    const int lane = tid & 63;
    const int ty  = lane >> 2;     // 0..15 tile row
    const int tx4 = lane & 3;      // pixel group: x-local 4*tx4 .. 4*tx4+3

    __shared__ float  xs[2 * 1024];             // [buf][ch][16][16] current tile
    __shared__ float  ps[2 * 2304];             // [buf][ch][24][24] prev halo
    __shared__ double ivq[24 * 25];             // prev inv-norms (halo), 0 if OOB
    __shared__ double ivp[256];                 // current inv-norms
    __shared__ unsigned long long red[256];     // packed argmax, slot = ty + col*16

    const float*  xcur    = x    + (size_t)b * (CHN * HW);
    const float*  xprv    = x    + (size_t)(b - 1) * (CHN * HW);
    const double* inv_cur = invn + (size_t)b * HW;
    const double* inv_prv = invn + (size_t)(b - 1) * HW;

    // stage inverse norms + init reduction slots (576 = 24*24 exactly)
    {
        int row = tid / 24, col = tid - row * 24;
        int gy = y0 - 4 + row, gx = x0 - 4 + col;
        double v = 0.0;
        if (gy >= 0 && gy < HH && gx >= 0 && gx < WW) v = inv_prv[gy * WW + gx];
        ivq[row * 25 + col] = v;
    }
    if (tid < 256) {
        ivp[tid] = inv_cur[(y0 + (tid >> 4)) * WW + x0 + (tid & 15)];
        red[tid] = 0ULL;
    }

    // staging descriptors: ps (4ch*24rows*6grp = 576 lanes, float idx = tid*4),
    // xs (4ch*16rows*4grp = 256 lanes, float idx = tid*4)
    int ch_s  = tid / 144;
    int rem_s = tid - ch_s * 144;
    int row_s = rem_s / 6;
    int c4    = rem_s - row_s * 6;
    int gy_s  = y0 - 4 + row_s;
    int gx_s  = x0 - 4 + 4 * c4;
    const bool pv = (gy_s >= 0 && gy_s < HH && gx_s >= 0 && gx_s < WW); // never straddles
    const size_t ps_g = (size_t)ch_s * HW + (pv ? (gy_s * WW + gx_s) : 0);
    size_t xs_g = 0;
    if (tid < 256) {
        int chx = tid >> 6, r2 = tid & 63, sy = r2 >> 2, sx = r2 & 3;
        xs_g = (size_t)chx * HW + (size_t)(y0 + sy) * WW + x0 + 4 * sx;
    }
    // per-wave uniform LDS bases for the DMA (lane*16B appended by HW)
    const int wv = tid >> 6;
    float* const ps_w0 = &ps[wv * 256];             // + buf*2304
    float* const xs_w0 = &xs[wv * 256];             // + buf*1024 (waves 0-3 only)

    // pre-zero cc-invariant OOB halo slots in BOTH buffers (DMA never writes them)
    if (!pv) {
        *(float4*)&ps[tid * 4]        = make_float4(0.f, 0.f, 0.f, 0.f);
        *(float4*)&ps[2304 + tid * 4] = make_float4(0.f, 0.f, 0.f, 0.f);
    }

    // prologue: DMA cc=0 into buffer 0
    if (pv) dma16(xprv + ps_g, ps_w0);
    if (tid < 256) dma16(xcur + xs_g, xs_w0);

    float acc[9][4];
    #pragma unroll
    for (int j = 0; j < 9; ++j)
        #pragma unroll
        for (int t = 0; t < 4; ++t) acc[j][t] = 0.f;

    __syncthreads();   // vmcnt(0) drain: buffer 0 ready; ivq/ivp/red visible

    for (int cc = 0; cc < 64; ++cc) {
        const int cur = cc & 1;
        // issue next stage BEFORE compute: latency hides under LDS reads + FMAs
        if (cc < 63) {
            const size_t cb = (size_t)((cc + 1) * 4) * HW;
            const int nxt = cur ^ 1;
            if (pv) dma16(xprv + cb + ps_g, ps_w0 + nxt * 2304);
            if (tid < 256) dma16(xcur + cb + xs_g, xs_w0 + nxt * 1024);
        }

        const float* xb = &xs[cur * 1024 + ty * 16 + 4 * tx4];
        const float* pb = &ps[cur * 2304 + (ty + wave) * 24 + 4 * tx4];
        #pragma unroll
        for (int ch = 0; ch < 4; ++ch) {
            float4 xq = *(const float4*)(xb + ch * 256);
            float4 w0 = *(const float4*)(pb + ch * 576);
            float4 w1 = *(const float4*)(pb + ch * 576 + 4);
            float4 w2 = *(const float4*)(pb + ch * 576 + 8);
            float win[12] = { w0.x, w0.y, w0.z, w0.w,
                              w1.x, w1.y, w1.z, w1.w,
                              w2.x, w2.y, w2.z, w2.w };
            #pragma unroll
            for (int dx = 0; dx < 9; ++dx) {
                acc[dx][0] = fmaf(xq.x, win[dx + 0], acc[dx][0]);
                acc[dx][1] = fmaf(xq.y, win[dx + 1], acc[dx][1]);
                acc[dx][2] = fmaf(xq.z, win[dx + 2], acc[dx][2]);
                acc[dx][3] = fmaf(xq.w, win[dx + 3], acc[dx][3]);
            }
        }
        // single barrier per cc: compiler emits vmcnt(0) here, draining the
        // next-stage DMA (issued one full compute phase ago) + releases cur buf
        __syncthreads();
    }

    // epilogue: local argmax over this wave's 9 offsets, packed-u64 merge
    const int px0 = ty * 16 + 4 * tx4;
    double ip[4];
    #pragma unroll
    for (int t = 0; t < 4; ++t) ip[t] = ivp[px0 + t];
    unsigned long long best[4] = { 0ULL, 0ULL, 0ULL, 0ULL };
    #pragma unroll
    for (int dx = 0; dx < 9; ++dx) {
        #pragma unroll
        for (int t = 0; t < 4; ++t) {
            double qv = ivq[(ty + wave) * 25 + 4 * tx4 + t + dx];
            float rv = (float)((double)acc[dx][t] * ip[t] * qv);
            unsigned int bits = __float_as_uint(rv);
            unsigned int key = (bits & 0x80000000u) ? ~bits : (bits | 0x80000000u);
            unsigned long long pk =
                ((unsigned long long)key << 32) | (unsigned int)(80 - (wave * 9 + dx));
            if (pk > best[t]) best[t] = pk;   // ascending dx + strict > == first-max
        }
    }
    #pragma unroll
    for (int t = 0; t < 4; ++t)
        atomicMax(&red[ty + ((4 * tx4 + t) << 4)], best[t]);   // bank-spread layout
    __syncthreads();

    if (tid < 256) {
        unsigned long long pk = red[(tid >> 4) + ((tid & 15) << 4)];
        int o = 80 - (int)(pk & 0xffffffffu);
        unsigned int key  = (unsigned int)(pk >> 32);
        unsigned int bits = (key & 0x80000000u) ? (key ^ 0x80000000u) : ~key;
        float v = __uint_as_float(bits);
        float h_idx = (float)(o / 9) - 4.f;
        float v_idx = (float)(o - (o / 9) * 9) - 4.f;
        // gaussian(sigma=0.1) zeroes all non-argmax cells below fp32 resolution:
        // h_cord = h_idx * R/(R+1e-12), R = BETA * r_max
        float R  = 10.f * v;
        float pc = R / (R + 1e-12f);
        int py = tid >> 4, pxl = tid & 15;
        int g = (y0 + py) * WW + (x0 + pxl);
        outb[g]          = h_idx * pc;
        outb[HW + g]     = v_idx * pc;
        outb[2 * HW + g] = v;
    }
}

extern "C" void kernel_launch(void* const* d_in, const int* in_sizes, int n_in,
                              void* d_out, int out_size, void* d_ws, size_t ws_size,
                              hipStream_t stream) {
    const float* x = (const float*)d_in[0];
    float* out = (float*)d_out;
    double* invn = (double*)d_ws;   // 200704 doubles = 1.6 MB

    hipLaunchKernelGGL(norm_kernel, dim3(NPIX / 256), dim3(256), 0, stream,
                       x, invn);
    hipLaunchKernelGGL(corr_kernel, dim3(16, 64), dim3(576), 0, stream,
                       x, invn, out);
}